// Round 1
// baseline (540.857 us; speedup 1.0000x reference)
//
#include <hip/hip_runtime.h>

// ---- problem constants ----
#define N_ROWS 8192
#define K_CODES 8192
#define C_DIM 128

// ---- ws layout (float indices) ----
#define WS_HN    0          // 8192 floats: 0.5*||e_k||^2
#define WS_PSC   8192       // 4*8192 floats: partial best score per (chunk,row)
#define WS_PIX   40960      // 4*8192 ints:   partial best index
#define WS_ET    73728      // 128*8192 floats: e transposed [c][k]
#define WS_XT    1122304    // 128*8192 floats: x transposed [c][n]
// total = 2,170,880 floats = 8,683,520 bytes of d_ws

// ---- out layout (float indices) ----
#define OUT_Q    0          // 1,048,576 floats [8,128,32,32]
#define OUT_ENC  1048576    // 67,108,864 floats [8192][8192]

// K1: transpose x and e into c-major layout in ws; fused half-norms for e.
__global__ __launch_bounds__(256) void k1_transpose(const float* __restrict__ x,
                                                    const float* __restrict__ e,
                                                    float* __restrict__ ws) {
    __shared__ float tl[128 * 64];
    int bx = blockIdx.x;              // 0..255 : first 128 do e, next 128 do x
    bool is_e = bx < 128;
    const float* src = is_e ? e : x;
    float* dst = ws + (is_e ? WS_ET : WS_XT);
    int k0 = (bx & 127) * 64;
    int tid = threadIdx.x;

    #pragma unroll
    for (int i = 0; i < 8; i++) {
        int g = tid + i * 256;        // 2048 float4 granules (64 rows x 32 f4)
        int kl = g >> 5, c4 = g & 31;
        float4 v = *(const float4*)(src + (size_t)(k0 + kl) * 128 + c4 * 4);
        tl[(c4 * 4 + 0) * 64 + kl] = v.x;
        tl[(c4 * 4 + 1) * 64 + kl] = v.y;
        tl[(c4 * 4 + 2) * 64 + kl] = v.z;
        tl[(c4 * 4 + 3) * 64 + kl] = v.w;
        if (is_e) {
            // 32 lanes (c4=0..31) of this 32-lane segment share kl -> reduce
            float s = v.x * v.x + v.y * v.y + v.z * v.z + v.w * v.w;
            for (int off = 16; off > 0; off >>= 1) s += __shfl_down(s, off, 32);
            if ((tid & 31) == 0) ws[WS_HN + k0 + kl] = 0.5f * s;
        }
    }
    __syncthreads();
    #pragma unroll
    for (int i = 0; i < 8; i++) {
        int g = tid + i * 256;        // 2048 float4 out (128 c-rows x 16 f4)
        int c = g >> 4, kc4 = g & 15;
        float4 v = *(const float4*)&tl[c * 64 + kc4 * 4];
        *(float4*)(dst + (size_t)c * 8192 + k0 + kc4 * 4) = v;
    }
}

// K2: fused distance-GEMM + per-chunk argmax + zero-fill of encodings.
// grid (64,4): 64 row-tiles of 128 rows, 4 k-chunks of 2048 codes. 256 thr.
__global__ __launch_bounds__(256, 1) void k2_argmax(float* __restrict__ ws,
                                                    float* __restrict__ out) {
    __shared__ float xs[128 * 128];   // [c][row]  64 KB
    __shared__ float es[128 * 128];   // [c][code] 64 KB
    int tid = threadIdx.x;
    int tr = tid >> 4;                // row group  (8 rows)
    int tc = tid & 15;                // code group (8 codes)
    int bx = blockIdx.x;              // row tile
    int by = blockIdx.y;              // k chunk
    int r0 = bx * 128;
    int kbase = by * 2048;
    const float* et = ws + WS_ET;
    const float* xt = ws + WS_XT;
    const float* hn = ws + WS_HN;

    // stage x tile (once): straight linear copy, conflict-free
    #pragma unroll
    for (int i = 0; i < 16; i++) {
        int g = tid + i * 256;
        *(float4*)&xs[g * 4] =
            *(const float4*)(xt + (size_t)(g >> 5) * 8192 + r0 + (g & 31) * 4);
    }
    // register prefetch of first e tile (64 KB / block -> 16 f4 per thread)
    float4 pf[16];
    #pragma unroll
    for (int i = 0; i < 16; i++) {
        int g = tid + i * 256;
        pf[i] = *(const float4*)(et + (size_t)(g >> 5) * 8192 + kbase + (g & 31) * 4);
    }

    float acc[8][8];
    float best[8];
    int bidx[8];
    #pragma unroll
    for (int i = 0; i < 8; i++) { best[i] = -3.0e38f; bidx[i] = 0; }

    float4* enc4 = (float4*)(out + OUT_ENC);
    long zb = (long)(by * 64 + bx) * 65536;   // this block's zero-fill region (f4)
    float4 z4 = make_float4(0.f, 0.f, 0.f, 0.f);

    for (int kt = 0; kt < 16; kt++) {
        int k0 = kbase + kt * 128;
        __syncthreads();              // previous tile's compute done
        #pragma unroll
        for (int i = 0; i < 16; i++) {
            int g = tid + i * 256;
            *(float4*)&es[g * 4] = pf[i];
        }
        if (kt < 15) {
            #pragma unroll
            for (int i = 0; i < 16; i++) {
                int g = tid + i * 256;
                pf[i] = *(const float4*)(et + (size_t)(g >> 5) * 8192 +
                                         (k0 + 128) + (g & 31) * 4);
            }
        }
        // fused zero-fill of encodings (rides the idle memory pipe)
        #pragma unroll
        for (int i = 0; i < 16; i++) enc4[zb + kt * 4096 + i * 256 + tid] = z4;

        float4 h0 = *(const float4*)(hn + k0 + tc * 8);
        float4 h1 = *(const float4*)(hn + k0 + tc * 8 + 4);
        #pragma unroll
        for (int i = 0; i < 8; i++)
            #pragma unroll
            for (int j = 0; j < 8; j++) acc[i][j] = 0.f;
        __syncthreads();              // es tile visible

        #pragma unroll 2
        for (int c = 0; c < 128; c++) {
            float4 xa = *(const float4*)&xs[c * 128 + tr * 8];
            float4 xb = *(const float4*)&xs[c * 128 + tr * 8 + 4];
            float4 ea = *(const float4*)&es[c * 128 + tc * 8];
            float4 eb = *(const float4*)&es[c * 128 + tc * 8 + 4];
            float xr[8] = {xa.x, xa.y, xa.z, xa.w, xb.x, xb.y, xb.z, xb.w};
            float er[8] = {ea.x, ea.y, ea.z, ea.w, eb.x, eb.y, eb.z, eb.w};
            #pragma unroll
            for (int i = 0; i < 8; i++)
                #pragma unroll
                for (int j = 0; j < 8; j++) acc[i][j] += xr[i] * er[j];
        }
        float hv[8] = {h0.x, h0.y, h0.z, h0.w, h1.x, h1.y, h1.z, h1.w};
        #pragma unroll
        for (int i = 0; i < 8; i++) {
            #pragma unroll
            for (int j = 0; j < 8; j++) {
                float s = acc[i][j] - hv[j];
                // strict > keeps the earliest (smallest) k on ties
                if (s > best[i]) { best[i] = s; bidx[i] = k0 + tc * 8 + j; }
            }
        }
    }

    // cross-thread reduce (16 tc-groups per row) via LDS, tie-break on index
    __syncthreads();
    float* red_s = xs;                // reuse: [128][16]
    int* red_i = (int*)(xs + 2048);
    #pragma unroll
    for (int i = 0; i < 8; i++) {
        red_s[(tr * 8 + i) * 16 + tc] = best[i];
        red_i[(tr * 8 + i) * 16 + tc] = bidx[i];
    }
    __syncthreads();
    if (tid < 128) {
        float b = red_s[tid * 16];
        int bi = red_i[tid * 16];
        for (int t = 1; t < 16; t++) {
            float s = red_s[tid * 16 + t];
            int ii = red_i[tid * 16 + t];
            if (s > b || (s == b && ii < bi)) { b = s; bi = ii; }
        }
        ws[WS_PSC + by * 8192 + r0 + tid] = b;
        ((int*)ws)[WS_PIX + by * 8192 + r0 + tid] = bi;
    }
}

// K3: combine 4 chunk-partials, write one-hot 1.0, gather + NCHW-write quantized
__global__ __launch_bounds__(256) void k3_final(const float* __restrict__ ws,
                                                const float* __restrict__ wgt,
                                                float* __restrict__ out) {
    int n = blockIdx.x * 256 + threadIdx.x;   // 0..8191
    float b = ws[WS_PSC + n];
    int bi = ((const int*)ws)[WS_PIX + n];
    #pragma unroll
    for (int ch = 1; ch < 4; ch++) {
        float s = ws[WS_PSC + ch * 8192 + n];
        int ii = ((const int*)ws)[WS_PIX + ch * 8192 + n];
        if (s > b || (s == b && ii < bi)) { b = s; bi = ii; }
    }
    out[(size_t)OUT_ENC + (size_t)n * 8192 + bi] = 1.0f;

    // out0[((bq*128 + c)*32 + h)*32 + w], n = bq*1024 + h*32 + w
    int bq = n >> 10, hw = n & 1023;
    float* o = out + (size_t)bq * 131072 + hw;      // +c*1024 per channel
    const float4* wrow = (const float4*)(wgt + (size_t)bi * 128);
    #pragma unroll
    for (int c4 = 0; c4 < 32; c4++) {
        float4 v = wrow[c4];
        o[(c4 * 4 + 0) * 1024] = v.x;
        o[(c4 * 4 + 1) * 1024] = v.y;
        o[(c4 * 4 + 2) * 1024] = v.z;
        o[(c4 * 4 + 3) * 1024] = v.w;
    }
}

extern "C" void kernel_launch(void* const* d_in, const int* in_sizes, int n_in,
                              void* d_out, int out_size, void* d_ws, size_t ws_size,
                              hipStream_t stream) {
    const float* x = (const float*)d_in[0];   // [8,32,32,128] fp32 -> [8192][128]
    const float* e = (const float*)d_in[1];   // [8192][128] fp32
    float* out = (float*)d_out;
    float* ws = (float*)d_ws;                 // needs ~8.7 MB

    k1_transpose<<<256, 256, 0, stream>>>(x, e, ws);
    k2_argmax<<<dim3(64, 4), 256, 0, stream>>>(ws, out);
    k3_final<<<32, 256, 0, stream>>>(ws, e, out);
}

// Round 2
// 328.425 us; speedup vs baseline: 1.6468x; 1.6468x over previous
//
#include <hip/hip_runtime.h>

typedef _Float16 f16x4 __attribute__((ext_vector_type(4)));
typedef _Float16 f16x8 __attribute__((ext_vector_type(8)));
typedef float    f32x16 __attribute__((ext_vector_type(16)));

// ---- ws byte offsets (total 8,486,912 B <= prior-known-good 8,683,520) ----
#define HN_OFF   0u                      // 8192 fp32: 0.5*||e||^2   (32 KB)
#define BEST_OFF 32768u                  // 8192 u64 packed best     (64 KB)
#define ERH_OFF  98304u                  // 8192x128 f16 e-hi        (2 MB)
#define ERL_OFF  (98304u + 2097152u)     // e-lo * 2^11
#define XRH_OFF  (98304u + 2u * 2097152u) // x-hi
#define XRL_OFF  (98304u + 3u * 2097152u) // x-lo * 2^11

// ---- out layout (float indices): [quantized NCHW 1M][encodings 64M] ----
#define OUT_Q    0
#define OUT_ENC  1048576

// K1: split x,e into f16 hi + scaled-lo planes (row-major); fused 0.5*||e||^2;
//     zero-init packed-best array.
__global__ __launch_bounds__(256) void k1_convert(const float* __restrict__ x,
                                                  const float* __restrict__ e,
                                                  char* __restrict__ wsb) {
    int bx = blockIdx.x, tid = threadIdx.x;
    bool is_e = bx < 1024;
    const float* src = is_e ? e : x;
    int sec = is_e ? bx : bx - 1024;
    size_t off = (size_t)sec * 1024 + tid * 4;      // float-element offset
    float4 v = *(const float4*)(src + off);

    f16x4 hi, lo;
    hi[0] = (_Float16)v.x; hi[1] = (_Float16)v.y;
    hi[2] = (_Float16)v.z; hi[3] = (_Float16)v.w;
    lo[0] = (_Float16)((v.x - (float)hi[0]) * 2048.0f);
    lo[1] = (_Float16)((v.y - (float)hi[1]) * 2048.0f);
    lo[2] = (_Float16)((v.z - (float)hi[2]) * 2048.0f);
    lo[3] = (_Float16)((v.w - (float)hi[3]) * 2048.0f);

    _Float16* ph = (_Float16*)(wsb + (is_e ? ERH_OFF : XRH_OFF));
    _Float16* pl = (_Float16*)(wsb + (is_e ? ERL_OFF : XRL_OFF));
    *(f16x4*)(ph + off) = hi;
    *(f16x4*)(pl + off) = lo;

    if (is_e) {
        float s = v.x * v.x + v.y * v.y + v.z * v.z + v.w * v.w;
        for (int o = 16; o > 0; o >>= 1) s += __shfl_down(s, o, 32);
        if ((tid & 31) == 0)
            ((float*)(wsb + HN_OFF))[off >> 7] = 0.5f * s;   // row = off/128
    } else if (sec < 32) {
        ((unsigned long long*)(wsb + BEST_OFF))[sec * 256 + tid] = 0ull;
    }
}

// K2: 3-product f16-split MFMA argmax. grid (64 row-tiles, 8 code-chunks).
// Block: 128 rows x 1024 codes. Wave w: rows +w*32 (m = lane&31).
// Fused zero-fill of the 64M-float encodings output.
__global__ __launch_bounds__(256, 2) void k2_mfma(char* __restrict__ wsb,
                                                  float* __restrict__ out) {
    __shared__ _Float16 lds_eh[128 * 128];   // 32 KB, XOR-swizzled 16B chunks
    __shared__ _Float16 lds_el[128 * 128];   // 32 KB
    __shared__ float    lds_hn[1024];        // 4 KB

    const _Float16* xrh = (const _Float16*)(wsb + XRH_OFF);
    const _Float16* xrl = (const _Float16*)(wsb + XRL_OFF);
    const _Float16* erh = (const _Float16*)(wsb + ERH_OFF);
    const _Float16* erl = (const _Float16*)(wsb + ERL_OFF);
    const float* hn = (const float*)(wsb + HN_OFF);
    unsigned long long* bestg = (unsigned long long*)(wsb + BEST_OFF);

    int tid = threadIdx.x;
    int lane = tid & 63, wave = tid >> 6;
    int col = lane & 31, half = lane >> 5;
    int bx = blockIdx.x, by = blockIdx.y;
    int r0 = bx * 128;
    int k0g = by * 1024;
    int row = r0 + wave * 32 + col;          // A-operand m = lane&31

    // A fragments in registers for the whole kernel:
    // A[m][k], k = half*8 + j within each K=16 step s (c = s*16 + k)
    f16x8 ah[8], al[8];
    #pragma unroll
    for (int s = 0; s < 8; s++) {
        ah[s] = *(const f16x8*)(xrh + (size_t)row * 128 + s * 16 + half * 8);
        al[s] = *(const f16x8*)(xrl + (size_t)row * 128 + s * 16 + half * 8);
    }

    // stage this chunk's half-norms (1024 fp32)
    *(float4*)(lds_hn + tid * 4) = *(const float4*)(hn + k0g + tid * 4);

    float best[16];
    int bidx[16];
    #pragma unroll
    for (int i = 0; i < 16; i++) { best[i] = -3.0e38f; bidx[i] = 0; }

    float4* enc4 = (float4*)(out + OUT_ENC);
    long zb = (long)(by * 64 + bx) * 32768;  // this block's zero region (f4)
    float4 z4 = make_float4(0.f, 0.f, 0.f, 0.f);

    for (int kt = 0; kt < 8; kt++) {
        __syncthreads();                      // prev tile consumed (also hn vis)
        // stage e-tile (128 codes x 128 c, hi+lo): 4096 16B chunks, 16/thread.
        // swizzle: chunk c16 stored at c16 ^ (code&15) -> conflict-free b128.
        #pragma unroll
        for (int i = 0; i < 16; i++) {
            int g = tid + i * 256;
            int gg = g & 2047;
            int code = gg >> 4, c16 = gg & 15;
            const _Float16* srcp = (i < 8) ? erh : erl;
            f16x8 v = *(const f16x8*)(srcp +
                         (size_t)(k0g + kt * 128 + code) * 128 + c16 * 8);
            _Float16* dstp = (i < 8) ? lds_eh : lds_el;
            *(f16x8*)(dstp + code * 128 + ((c16 ^ (code & 15)) * 8)) = v;
        }
        // fused zero-fill of encodings (rides the store pipe)
        #pragma unroll
        for (int i = 0; i < 16; i++) enc4[zb + kt * 4096 + i * 256 + tid] = z4;
        __syncthreads();                      // tile visible

        #pragma unroll
        for (int sub = 0; sub < 4; sub++) {
            f32x16 a0, a1, a2;
            #pragma unroll
            for (int i = 0; i < 16; i++) { a0[i] = 0.f; a1[i] = 0.f; a2[i] = 0.f; }
            int cbase = (sub * 32 + col) * 128;   // B n-index = lane&31
            #pragma unroll
            for (int s = 0; s < 8; s++) {
                int so = ((s * 2 + half) ^ (col & 15)) * 8;
                f16x8 bh = *(const f16x8*)(lds_eh + cbase + so);
                f16x8 bl = *(const f16x8*)(lds_el + cbase + so);
                a0 = __builtin_amdgcn_mfma_f32_32x32x16_f16(ah[s], bh, a0, 0, 0, 0);
                a1 = __builtin_amdgcn_mfma_f32_32x32x16_f16(ah[s], bl, a1, 0, 0, 0);
                a2 = __builtin_amdgcn_mfma_f32_32x32x16_f16(al[s], bh, a2, 0, 0, 0);
            }
            int code = k0g + kt * 128 + sub * 32 + col;
            float hnv = lds_hn[kt * 128 + sub * 32 + col];
            #pragma unroll
            for (int r = 0; r < 16; r++) {
                float sc = a0[r] + (a1[r] + a2[r]) * (1.0f / 2048.0f) - hnv;
                if (sc > best[r]) { best[r] = sc; bidx[r] = code; }  // > keeps first
            }
        }
    }

    // reduce across the 32 cols (same half-wave), then device atomicMax.
    // C/D row = (r&3) + 8*(r>>2) + 4*half ; col = lane&31.
    #pragma unroll
    for (int r = 0; r < 16; r++) {
        float s = best[r];
        int bi = bidx[r];
        #pragma unroll
        for (int m = 1; m < 32; m <<= 1) {
            float qs = __shfl_xor(s, m, 64);
            int qi = __shfl_xor(bi, m, 64);
            if (qs > s || (qs == s && qi < bi)) { s = qs; bi = qi; }
        }
        if (col == 0) {
            int rl = (r & 3) + 8 * (r >> 2) + 4 * half;
            unsigned ub = __float_as_uint(s);
            ub = ((int)ub < 0) ? ~ub : (ub | 0x80000000u);   // sortable map
            unsigned long long p = ((unsigned long long)ub << 32) |
                                   (unsigned long long)(0xFFFFFFFFu - (unsigned)bi);
            atomicMax(&bestg[r0 + wave * 32 + rl], p);       // tie -> min idx
        }
    }
}

// K3: decode packed best, write one-hot 1.0, gather e[bi] -> NCHW output.
__global__ __launch_bounds__(256) void k3_final(const char* __restrict__ wsb,
                                                const float* __restrict__ wgt,
                                                float* __restrict__ out) {
    int n = blockIdx.x * 256 + threadIdx.x;   // 0..8191
    unsigned long long p = ((const unsigned long long*)(wsb + BEST_OFF))[n];
    int bi = (int)(0xFFFFFFFFu - (unsigned)(p & 0xFFFFFFFFull));

    out[(size_t)OUT_ENC + (size_t)n * 8192 + bi] = 1.0f;

    // out0[((bq*128 + c)*32 + h)*32 + w], n = bq*1024 + h*32 + w
    int bq = n >> 10, hw = n & 1023;
    float* o = out + (size_t)bq * 131072 + hw;
    const float4* wrow = (const float4*)(wgt + (size_t)bi * 128);
    #pragma unroll
    for (int c4 = 0; c4 < 32; c4++) {
        float4 v = wrow[c4];
        o[(c4 * 4 + 0) * 1024] = v.x;
        o[(c4 * 4 + 1) * 1024] = v.y;
        o[(c4 * 4 + 2) * 1024] = v.z;
        o[(c4 * 4 + 3) * 1024] = v.w;
    }
}

extern "C" void kernel_launch(void* const* d_in, const int* in_sizes, int n_in,
                              void* d_out, int out_size, void* d_ws, size_t ws_size,
                              hipStream_t stream) {
    const float* x = (const float*)d_in[0];   // [8,32,32,128] -> [8192][128]
    const float* e = (const float*)d_in[1];   // [8192][128]
    float* out = (float*)d_out;
    char* ws = (char*)d_ws;

    k1_convert<<<2048, 256, 0, stream>>>(x, e, ws);
    k2_mfma<<<dim3(64, 8), 256, 0, stream>>>(ws, out);
    k3_final<<<32, 256, 0, stream>>>(ws, e, out);
}